// Round 3
// baseline (334.022 us; speedup 1.0000x reference)
//
#include <hip/hip_runtime.h>
#include <hip/hip_fp16.h>

#define RANK 12
#define RES 192
#define NHW (RES * RES)
#define NF 36
#define ODIM 32
#define TEXW 16   // halfs per texel (12 used + 4 pad) -> 32 B, 16B-aligned loads

typedef float f32x4 __attribute__((ext_vector_type(4)));   // native vec for nt builtins

// ---------------------------------------------------------------------------
// Pre-pass: transpose planes [R][H][W] f32 -> [3][H][W][16] fp16.
// 32 B per texel; halfs 12..15 zeroed. 3.54 MB total -> fits per-XCD L2.
// ---------------------------------------------------------------------------
__global__ __launch_bounds__(256) void vme_transpose(const float* __restrict__ a,
                                                     const float* __restrict__ b,
                                                     const float* __restrict__ c,
                                                     _Float16* __restrict__ t) {
    int idx = blockIdx.x * 256 + threadIdx.x;
    if (idx >= 3 * NHW) return;
    int p = idx / NHW;
    int yx = idx - p * NHW;
    const float* src = (p == 0) ? a : (p == 1) ? b : c;
    _Float16* dst = t + (size_t)idx * TEXW;
#pragma unroll
    for (int r = 0; r < RANK; ++r) dst[r] = (_Float16)src[(size_t)r * NHW + yx];
#pragma unroll
    for (int r = RANK; r < TEXW; ++r) dst[r] = (_Float16)0.0f;
}

__device__ inline void decode_texel(const _Float16* __restrict__ tex, float* __restrict__ o) {
    // texel = 32 B aligned: load 16B + 8B, use first 12 halfs
    union { uint4 v; _Float16 h[8]; } A;
    union { uint2 v; _Float16 h[4]; } B;
    A.v = *(const uint4*)(tex);
    B.v = *(const uint2*)(tex + 8);
#pragma unroll
    for (int r = 0; r < 8; ++r) o[r] = (float)A.h[r];
#pragma unroll
    for (int r = 0; r < 4; ++r) o[8 + r] = (float)B.h[r];
}

// ---------------------------------------------------------------------------
// Main kernel: one thread per point. fp16 L2-resident planes, nt in/out.
// ---------------------------------------------------------------------------
__global__ __launch_bounds__(256) void vme_main(const float* __restrict__ xyz,
                                                const _Float16* __restrict__ tp,
                                                const float* __restrict__ w,
                                                float* __restrict__ out,
                                                int n) {
    int i = blockIdx.x * 256 + threadIdx.x;
    if (i >= n) return;

    float px = __builtin_nontemporal_load(xyz + 3 * (size_t)i + 0);
    float py = __builtin_nontemporal_load(xyz + 3 * (size_t)i + 1);
    float pz = __builtin_nontemporal_load(xyz + 3 * (size_t)i + 2);

    float f[NF];

    float us[3] = {px, px, py};
    float vs[3] = {py, pz, pz};

#pragma unroll
    for (int p = 0; p < 3; ++p) {
        float x = us[p] * (float)(RES - 1);
        float y = vs[p] * (float)(RES - 1);
        x = fminf(fmaxf(x, 0.0f), (float)(RES - 1));
        y = fminf(fmaxf(y, 0.0f), (float)(RES - 1));
        int x0 = (int)x;
        int y0 = (int)y;
        int x1 = min(x0 + 1, RES - 1);
        int y1 = min(y0 + 1, RES - 1);
        float wx = x - (float)x0;
        float wy = y - (float)y0;
        float w00 = (1.0f - wx) * (1.0f - wy);
        float w01 = wx * (1.0f - wy);
        float w10 = (1.0f - wx) * wy;
        float w11 = wx * wy;

        const _Float16* base = tp + (size_t)p * NHW * TEXW;
        const _Float16* t00 = base + (size_t)(y0 * RES + x0) * TEXW;
        const _Float16* t01 = base + (size_t)(y0 * RES + x1) * TEXW;
        const _Float16* t10 = base + (size_t)(y1 * RES + x0) * TEXW;
        const _Float16* t11 = base + (size_t)(y1 * RES + x1) * TEXW;

        float d00[RANK], d01[RANK], d10[RANK], d11[RANK];
        decode_texel(t00, d00);
        decode_texel(t01, d01);
        decode_texel(t10, d10);
        decode_texel(t11, d11);
#pragma unroll
        for (int r = 0; r < RANK; ++r) {
            f[p * RANK + r] = w00 * d00[r] + w01 * d01[r] + w10 * d10[r] + w11 * d11[r];
        }
    }

    // Dense layer: wave-uniform weights at constant offsets -> SGPR operands.
    float acc[ODIM];
#pragma unroll
    for (int o = 0; o < ODIM; ++o) {
        float s = 0.0f;
#pragma unroll
        for (int k = 0; k < NF; ++k) s += f[k] * w[o * NF + k];
        acc[o] = s;
    }

    float* op = out + (size_t)i * ODIM;
#pragma unroll
    for (int q = 0; q < 8; ++q) {
        f32x4 v = {acc[4 * q + 0], acc[4 * q + 1], acc[4 * q + 2], acc[4 * q + 3]};
        __builtin_nontemporal_store(v, (f32x4*)(op + 4 * q));
    }
}

// Fallback (ws too small): sample original planes directly.
__global__ __launch_bounds__(256) void vme_main_fb(const float* __restrict__ xyz,
                                                   const float* __restrict__ pa,
                                                   const float* __restrict__ pb,
                                                   const float* __restrict__ pc,
                                                   const float* __restrict__ w,
                                                   float* __restrict__ out,
                                                   int n) {
    int i = blockIdx.x * 256 + threadIdx.x;
    if (i >= n) return;
    float px = xyz[3 * (size_t)i + 0];
    float py = xyz[3 * (size_t)i + 1];
    float pz = xyz[3 * (size_t)i + 2];
    float f[NF];
    float us[3] = {px, px, py};
    float vs[3] = {py, pz, pz};
#pragma unroll
    for (int p = 0; p < 3; ++p) {
        float x = us[p] * (float)(RES - 1);
        float y = vs[p] * (float)(RES - 1);
        x = fminf(fmaxf(x, 0.0f), (float)(RES - 1));
        y = fminf(fmaxf(y, 0.0f), (float)(RES - 1));
        int x0 = (int)x;
        int y0 = (int)y;
        int x1 = min(x0 + 1, RES - 1);
        int y1 = min(y0 + 1, RES - 1);
        float wx = x - (float)x0;
        float wy = y - (float)y0;
        float w00 = (1.0f - wx) * (1.0f - wy);
        float w01 = wx * (1.0f - wy);
        float w10 = (1.0f - wx) * wy;
        float w11 = wx * wy;
        const float* base = (p == 0) ? pa : (p == 1) ? pb : pc;
        int i00 = y0 * RES + x0, i01 = y0 * RES + x1;
        int i10 = y1 * RES + x0, i11 = y1 * RES + x1;
#pragma unroll
        for (int r = 0; r < RANK; ++r) {
            const float* pr = base + (size_t)r * NHW;
            f[p * RANK + r] = w00 * pr[i00] + w01 * pr[i01] + w10 * pr[i10] + w11 * pr[i11];
        }
    }
    float acc[ODIM];
#pragma unroll
    for (int o = 0; o < ODIM; ++o) {
        float s = 0.0f;
#pragma unroll
        for (int k = 0; k < NF; ++k) s += f[k] * w[o * NF + k];
        acc[o] = s;
    }
    float4* op = (float4*)(out + (size_t)i * ODIM);
#pragma unroll
    for (int q = 0; q < 8; ++q)
        op[q] = make_float4(acc[4 * q], acc[4 * q + 1], acc[4 * q + 2], acc[4 * q + 3]);
}

extern "C" void kernel_launch(void* const* d_in, const int* in_sizes, int n_in,
                              void* d_out, int out_size, void* d_ws, size_t ws_size,
                              hipStream_t stream) {
    const float* xyz = (const float*)d_in[0];
    const float* xy  = (const float*)d_in[1];
    const float* xz  = (const float*)d_in[2];
    const float* yz  = (const float*)d_in[3];
    const float* wml = (const float*)d_in[4];
    float* out = (float*)d_out;

    int n = in_sizes[0] / 3;
    int nblk = (n + 255) / 256;

    const size_t tbytes = (size_t)3 * NHW * TEXW * sizeof(_Float16);
    bool use_tr = (ws_size >= tbytes) && (d_ws != nullptr);

    if (use_tr) {
        _Float16* tp = (_Float16*)d_ws;
        int tblk = (3 * NHW + 255) / 256;
        vme_transpose<<<tblk, 256, 0, stream>>>(xy, xz, yz, tp);
        vme_main<<<nblk, 256, 0, stream>>>(xyz, tp, wml, out, n);
    } else {
        vme_main_fb<<<nblk, 256, 0, stream>>>(xyz, xy, xz, yz, wml, out, n);
    }
}